// Round 1
// baseline (1409.665 us; speedup 1.0000x reference)
//
#include <hip/hip_runtime.h>
#include <hip/hip_bf16.h>
#include <stdint.h>

// Problem constants (fixed by setup_inputs):
//   x: (4,4096,1024) f32 -> 16384 x 1024 rows
//   codebook: (16384,1024) f32
#define NROWS  16384
#define NCODES 16384
#define DIM    1024
#define NBLK   128           // NCODES / 128 column-blocks
#define MARGIN 3.0f          // ~20 sigma of bf16 approx-score error

typedef float f32x4  __attribute__((ext_vector_type(4)));
typedef short bf16x8 __attribute__((ext_vector_type(8)));

__device__ __forceinline__ ushort f2bf(float f) {
  uint32_t u = __float_as_uint(f);
  uint32_t r = u + 0x7FFFu + ((u >> 16) & 1u);   // round-to-nearest-even
  return (ushort)(r >> 16);
}

__device__ __forceinline__ uint64_t umin64(uint64_t a, uint64_t b){ return a < b ? a : b; }
__device__ __forceinline__ uint64_t umax64(uint64_t a, uint64_t b){ return a < b ? b : a; }

// Order-preserving float->u32 transform packed with index (low 32 bits).
__device__ __forceinline__ uint64_t packKey(float v, uint32_t idx) {
  uint32_t b = __float_as_uint(v);
  b = (b & 0x80000000u) ? ~b : (b | 0x80000000u);
  return ((uint64_t)b << 32) | idx;
}
__device__ __forceinline__ float unpackVal(uint64_t k) {
  uint32_t b = (uint32_t)(k >> 32);
  b = (b & 0x80000000u) ? (b & 0x7FFFFFFFu) : ~b;
  return __uint_as_float(b);
}

// ---------------- kernel 0: c2[c] = sum(codebook[c]^2) ----------------
__global__ __launch_bounds__(256) void c2_kernel(const float* __restrict__ cb,
                                                 float* __restrict__ c2) {
  const int code = blockIdx.x;
  const int t = threadIdx.x, lane = t & 63, wid = t >> 6;
  f32x4 v = *(const f32x4*)(cb + (size_t)code * DIM + t * 4);
  float s = v[0]*v[0] + v[1]*v[1] + v[2]*v[2] + v[3]*v[3];
  #pragma unroll
  for (int off = 32; off; off >>= 1) s += __shfl_down(s, off);
  __shared__ float part[4];
  if (lane == 0) part[wid] = s;
  __syncthreads();
  if (t == 0) c2[code] = part[0] + part[1] + part[2] + part[3];
}

// ---------------- kernel 1: bf16 MFMA GEMM + per-(row, 128-code-block) top-2 ----------------
// Scores s[n][c] = c2[c] - 2 * dot(x[n], cb[c])  (x2 omitted: row-constant).
// cand layout: cand[row * 256 + bn*2 + {0,1}] packed (orderedF32<<32 | codeIdx).
__global__ __launch_bounds__(256) void snap_gemm(const float* __restrict__ x,
                                                 const float* __restrict__ cb,
                                                 const float* __restrict__ c2,
                                                 uint64_t* __restrict__ cand) {
  __shared__ ushort lsA[2][8192];           // 128 rows x 64 bf16, chunk-swizzled
  __shared__ ushort lsB[2][8192];
  __shared__ uint64_t redbuf[2][128][2];    // [wn][row][top2]

  const int t    = threadIdx.x;
  const int lane = t & 63;
  const int wid  = t >> 6;
  const int wm   = wid & 1;       // wave row (2x2 wave grid, 64x64 out each)
  const int wn   = wid >> 1;      // wave col
  const int l15  = lane & 15;
  const int kgrp = lane >> 4;

  const int bm = blockIdx.x & 127;        // consecutive blocks share the codebook panel
  const int bn = blockIdx.x >> 7;
  const int rowBase = bm * 128;
  const int colBase = bn * 128;

  // --- staging addressing: 1024 16B-chunks per tile, 4 per thread.
  // phys chunk pc = row*8 + (g ^ (row&7));  thread handles pc = t + 256*i.
  const float* aptr[4];
  const float* bptr[4];
  int ldsOff[4];
  #pragma unroll
  for (int i = 0; i < 4; ++i) {
    int pc = t + 256 * i;
    int row = pc >> 3;
    int g = (pc & 7) ^ (row & 7);            // logical chunk this phys slot holds
    aptr[i] = x  + (size_t)(rowBase + row) * DIM + g * 8;
    bptr[i] = cb + (size_t)(colBase + row) * DIM + g * 8;
    ldsOff[i] = pc * 8;                      // ushort units (16B per chunk)
  }

  f32x4 acc[4][4];
  #pragma unroll
  for (int mi = 0; mi < 4; ++mi)
    #pragma unroll
    for (int ni = 0; ni < 4; ++ni)
      acc[mi][ni] = (f32x4){0.f, 0.f, 0.f, 0.f};

  auto STAGE = [&](int buf, int kt) {
    const int kOff = kt * 64;
    #pragma unroll
    for (int i = 0; i < 4; ++i) {
      f32x4 a0 = *(const f32x4*)(aptr[i] + kOff);
      f32x4 a1 = *(const f32x4*)(aptr[i] + kOff + 4);
      f32x4 b0 = *(const f32x4*)(bptr[i] + kOff);
      f32x4 b1 = *(const f32x4*)(bptr[i] + kOff + 4);
      bf16x8 pa, pb;
      #pragma unroll
      for (int j = 0; j < 4; ++j) {
        pa[j]     = (short)f2bf(a0[j]);
        pa[j + 4] = (short)f2bf(a1[j]);
        pb[j]     = (short)f2bf(b0[j]);
        pb[j + 4] = (short)f2bf(b1[j]);
      }
      *(bf16x8*)(&lsA[buf][ldsOff[i]]) = pa;
      *(bf16x8*)(&lsB[buf][ldsOff[i]]) = pb;
    }
  };

  STAGE(0, 0);
  __syncthreads();

  for (int kt = 0; kt < DIM / 64; ++kt) {
    const int cur = kt & 1;
    if (kt < DIM / 64 - 1) STAGE(cur ^ 1, kt + 1);

    const ushort* bA = &lsA[cur][0];
    const ushort* bB = &lsB[cur][0];
    #pragma unroll
    for (int ks = 0; ks < 2; ++ks) {
      const int gidx = ks * 4 + kgrp;        // logical chunk for this frag
      bf16x8 af[4], bfr[4];
      #pragma unroll
      for (int mi = 0; mi < 4; ++mi) {
        int r_ = wm * 64 + mi * 16 + l15;
        af[mi] = *(const bf16x8*)(bA + (r_ * 8 + (gidx ^ (r_ & 7))) * 8);
      }
      #pragma unroll
      for (int ni = 0; ni < 4; ++ni) {
        int c_ = wn * 64 + ni * 16 + l15;
        bfr[ni] = *(const bf16x8*)(bB + (c_ * 8 + (gidx ^ (c_ & 7))) * 8);
      }
      #pragma unroll
      for (int mi = 0; mi < 4; ++mi)
        #pragma unroll
        for (int ni = 0; ni < 4; ++ni)
          acc[mi][ni] = __builtin_amdgcn_mfma_f32_16x16x32_bf16(af[mi], bfr[ni], acc[mi][ni], 0, 0, 0);
    }
    __syncthreads();
  }

  // --- epilogue: per-row top-2 over this block's 128 columns ---
  float    c2v[4];
  uint32_t colv[4];
  #pragma unroll
  for (int ni = 0; ni < 4; ++ni) {
    colv[ni] = (uint32_t)(colBase + wn * 64 + ni * 16 + l15);
    c2v[ni]  = c2[colv[ni]];
  }

  #pragma unroll
  for (int mi = 0; mi < 4; ++mi) {
    #pragma unroll
    for (int r = 0; r < 4; ++r) {
      float s0 = c2v[0] - 2.0f * acc[mi][0][r];
      float s1 = c2v[1] - 2.0f * acc[mi][1][r];
      float s2 = c2v[2] - 2.0f * acc[mi][2][r];
      float s3 = c2v[3] - 2.0f * acc[mi][3][r];
      uint64_t a = packKey(s0, colv[0]);
      uint64_t b = packKey(s1, colv[1]);
      uint64_t c = packKey(s2, colv[2]);
      uint64_t d = packKey(s3, colv[3]);
      uint64_t lo1 = umin64(a, b), hi1 = umax64(a, b);
      uint64_t lo2 = umin64(c, d), hi2 = umax64(c, d);
      uint64_t k1 = umin64(lo1, lo2);
      uint64_t k2 = umin64(umax64(lo1, lo2), umin64(hi1, hi2));
      #pragma unroll
      for (int m = 1; m < 16; m <<= 1) {
        uint64_t o1 = __shfl_xor((unsigned long long)k1, m);
        uint64_t o2 = __shfl_xor((unsigned long long)k2, m);
        uint64_t n1 = umin64(k1, o1);
        uint64_t n2 = umin64(umax64(k1, o1), umin64(k2, o2));
        k1 = n1; k2 = n2;
      }
      if (l15 == 0) {
        int rl = wm * 64 + mi * 16 + kgrp * 4 + r;
        redbuf[wn][rl][0] = k1;
        redbuf[wn][rl][1] = k2;
      }
    }
  }
  __syncthreads();

  if (t < 128) {
    uint64_t a1 = redbuf[0][t][0], a2 = redbuf[0][t][1];
    uint64_t b1 = redbuf[1][t][0], b2 = redbuf[1][t][1];
    uint64_t m1 = umin64(a1, b1);
    uint64_t m2 = umin64(umax64(a1, b1), umin64(a2, b2));
    size_t o = (size_t)(rowBase + t) * (2 * NBLK) + (size_t)bn * 2;
    cand[o]     = m1;
    cand[o + 1] = m2;
  }
}

// ---------------- kernel 2: exact f64 rerank of candidates within MARGIN of pool-min ----------------
__global__ __launch_bounds__(256) void rerank(const float* __restrict__ x,
                                              const float* __restrict__ cb,
                                              const uint64_t* __restrict__ cand,
                                              int* __restrict__ bestidx) {
  const int row = blockIdx.x;
  const int t = threadIdx.x, lane = t & 63, wid = t >> 6;
  __shared__ uint64_t smin[4];
  __shared__ uint64_t gshared;
  __shared__ double   dpart[4];
  __shared__ int      cnt;
  __shared__ int      list[64];

  uint64_t my = cand[(size_t)row * 256 + t];
  uint64_t k = my;
  #pragma unroll
  for (int off = 32; off; off >>= 1) {
    uint64_t o = __shfl_down((unsigned long long)k, off);
    if (o < k) k = o;
  }
  if (lane == 0) smin[wid] = k;
  if (t == 0) cnt = 0;
  __syncthreads();
  if (t == 0) {
    uint64_t g = smin[0];
    for (int i = 1; i < 4; ++i) if (smin[i] < g) g = smin[i];
    gshared = g;
  }
  __syncthreads();

  float gval = unpackVal(gshared);
  if (unpackVal(my) <= gval + MARGIN) {
    int p = atomicAdd(&cnt, 1);
    if (p < 64) list[p] = (int)(uint32_t)(my & 0xFFFFFFFFu);
  }
  __syncthreads();
  int n = cnt; if (n > 64) n = 64;

  uint64_t best = ~0ull;
  const float* xr = x + (size_t)row * DIM;
  for (int i = 0; i < n; ++i) {
    const int cidx = list[i];
    const float* cr = cb + (size_t)cidx * DIM;
    double p = 0.0;
    #pragma unroll
    for (int j = 0; j < 4; ++j) {
      int d = t + 256 * j;
      double diff = (double)xr[d] - (double)cr[d];
      p += diff * diff;
    }
    #pragma unroll
    for (int off = 32; off; off >>= 1) p += __shfl_down(p, off);
    if (lane == 0) dpart[wid] = p;
    __syncthreads();
    if (t == 0) {
      double d2 = dpart[0] + dpart[1] + dpart[2] + dpart[3];
      uint64_t bits = (uint64_t)__double_as_longlong(d2);   // d2 >= 0: bits are order-preserving
      uint64_t key = (bits & ~0x3FFFull) | (uint32_t)cidx;  // low 14 bits: index (tie -> lowest idx)
      if (key < best) best = key;
    }
    __syncthreads();
  }
  if (t == 0) bestidx[row] = (int)(best & 0x3FFFull);
}

// ---------------- kernel 3: gather winning codebook rows ----------------
__global__ __launch_bounds__(256) void gather_rows(const float* __restrict__ cb,
                                                   const int* __restrict__ bestidx,
                                                   float* __restrict__ out) {
  const int row = blockIdx.x;
  const int idx = bestidx[row];
  f32x4 v = *(const f32x4*)(cb + (size_t)idx * DIM + threadIdx.x * 4);
  *(f32x4*)(out + (size_t)row * DIM + threadIdx.x * 4) = v;
}

extern "C" void kernel_launch(void* const* d_in, const int* in_sizes, int n_in,
                              void* d_out, int out_size, void* d_ws, size_t ws_size,
                              hipStream_t stream) {
  const float* x  = (const float*)d_in[0];
  const float* cb = (const float*)d_in[1];
  float* out = (float*)d_out;

  // Small scratch in d_ws (fully rewritten every call):
  float* c2      = (float*)d_ws;                        // 64 KB
  int*   bestidx = (int*)((char*)d_ws + 64 * 1024);     // 64 KB
  // Candidate pool (32 MB) lives in d_out (67 MB) and is consumed by rerank
  // before gather_rows overwrites d_out with the final result.
  uint64_t* cand = (uint64_t*)d_out;

  c2_kernel  <<<NCODES, 256, 0, stream>>>(cb, c2);
  snap_gemm  <<<(NROWS / 128) * (NCODES / 128), 256, 0, stream>>>(x, cb, c2, cand);
  rerank     <<<NROWS, 256, 0, stream>>>(x, cb, cand, bestidx);
  gather_rows<<<NROWS, 256, 0, stream>>>(cb, bestidx, out);
}

// Round 2
// 940.546 us; speedup vs baseline: 1.4988x; 1.4988x over previous
//
#include <hip/hip_runtime.h>
#include <hip/hip_bf16.h>
#include <stdint.h>

// Problem constants (fixed by setup_inputs):
//   x: (4,4096,1024) f32 -> 16384 x 1024 rows
//   codebook: (16384,1024) f32
#define NROWS  16384
#define NCODES 16384
#define DIM    1024
#define NBLK   128           // NCODES / 128 column-blocks
#define MARGIN 3.0f          // ~20 sigma of bf16 approx-score error

typedef float f32x4  __attribute__((ext_vector_type(4)));
typedef short bf16x8 __attribute__((ext_vector_type(8)));

__device__ __forceinline__ ushort f2bf(float f) {
  uint32_t u = __float_as_uint(f);
  uint32_t r = u + 0x7FFFu + ((u >> 16) & 1u);   // round-to-nearest-even
  return (ushort)(r >> 16);
}

__device__ __forceinline__ uint64_t umin64(uint64_t a, uint64_t b){ return a < b ? a : b; }
__device__ __forceinline__ uint64_t umax64(uint64_t a, uint64_t b){ return a < b ? b : a; }

// Order-preserving float->u32 transform packed with index (low 32 bits).
__device__ __forceinline__ uint64_t packKey(float v, uint32_t idx) {
  uint32_t b = __float_as_uint(v);
  b = (b & 0x80000000u) ? ~b : (b | 0x80000000u);
  return ((uint64_t)b << 32) | idx;
}
__device__ __forceinline__ float unpackVal(uint64_t k) {
  uint32_t b = (uint32_t)(k >> 32);
  b = (b & 0x80000000u) ? (b & 0x7FFFFFFFu) : ~b;
  return __uint_as_float(b);
}

// async 16B global->LDS (linear dest: base + lane*16)
#define GLDS16(gp, lp) \
  __builtin_amdgcn_global_load_lds((const __attribute__((address_space(1))) void*)(gp), \
                                   (__attribute__((address_space(3))) void*)(lp), 16, 0, 0)

// ---------------- kernel 0: c2[c] = sum(codebook[c]^2) ----------------
__global__ __launch_bounds__(256) void c2_kernel(const float* __restrict__ cb,
                                                 float* __restrict__ c2) {
  const int code = blockIdx.x;
  const int t = threadIdx.x, lane = t & 63, wid = t >> 6;
  f32x4 v = *(const f32x4*)(cb + (size_t)code * DIM + t * 4);
  float s = v[0]*v[0] + v[1]*v[1] + v[2]*v[2] + v[3]*v[3];
  #pragma unroll
  for (int off = 32; off; off >>= 1) s += __shfl_down(s, off);
  __shared__ float part[4];
  if (lane == 0) part[wid] = s;
  __syncthreads();
  if (t == 0) c2[code] = part[0] + part[1] + part[2] + part[3];
}

// ---------------- kernel 0b: f32 -> bf16, pre-swizzled tile-blocked layout ----------------
// dst chunk index: ((bm*16 + kt)*1024 + pc), 16B per chunk (8 bf16).
// chunk pc holds source row (pc>>3), logical k-chunk g = (pc&7) ^ (row&7).
// This bakes the LDS XOR-swizzle into the global layout so the GEMM can use
// global_load_lds with a LINEAR LDS destination (rule 21 / m173 pattern).
__global__ __launch_bounds__(256) void convert_swz(const float* __restrict__ src,
                                                   ushort* __restrict__ dst) {
  const int chunk = blockIdx.x * 256 + threadIdx.x;   // [0, 128*16*1024)
  const int pc  = chunk & 1023;
  const int kt  = (chunk >> 10) & 15;
  const int bm  = chunk >> 14;
  const int row = pc >> 3;
  const int g   = (pc & 7) ^ (row & 7);
  const float* s = src + (size_t)(bm * 128 + row) * DIM + kt * 64 + g * 8;
  f32x4 a0 = *(const f32x4*)s;
  f32x4 a1 = *(const f32x4*)(s + 4);
  bf16x8 p;
  #pragma unroll
  for (int j = 0; j < 4; ++j) {
    p[j]     = (short)f2bf(a0[j]);
    p[j + 4] = (short)f2bf(a1[j]);
  }
  *(bf16x8*)(dst + (size_t)chunk * 8) = p;
}

// ---------------- kernel 1 (fast): bf16 MFMA GEMM via global_load_lds + per-(row,128-block) top-2 ----------------
__global__ __launch_bounds__(256) void snap_gemm_fast(const ushort* __restrict__ xs,
                                                      const ushort* __restrict__ cs,
                                                      const float* __restrict__ c2,
                                                      uint64_t* __restrict__ cand) {
  __shared__ ushort lsA[2][8192];           // 128 rows x 64 bf16, chunk-swizzled
  __shared__ ushort lsB[2][8192];
  __shared__ uint64_t redbuf[2][128][2];    // [wn][row][top2]

  const int t    = threadIdx.x;
  const int lane = t & 63;
  const int wid  = t >> 6;
  const int wm   = wid & 1;       // wave row (2x2 wave grid, 64x64 out each)
  const int wn   = wid >> 1;      // wave col
  const int l15  = lane & 15;
  const int kgrp = lane >> 4;

  const int bm = blockIdx.x & 127;        // consecutive blocks share the codebook panel
  const int bn = blockIdx.x >> 7;

  f32x4 acc[4][4];
  #pragma unroll
  for (int mi = 0; mi < 4; ++mi)
    #pragma unroll
    for (int ni = 0; ni < 4; ++ni)
      acc[mi][ni] = (f32x4){0.f, 0.f, 0.f, 0.f};

  auto STAGE = [&](int buf, int kt) {
    const ushort* pa = xs + (size_t)(bm * 16 + kt) * 1024 * 8;
    const ushort* pb = cs + (size_t)(bn * 16 + kt) * 1024 * 8;
    #pragma unroll
    for (int i = 0; i < 4; ++i) {
      const int cbase = (i * 4 + wid) * 64;             // wave-uniform chunk base
      GLDS16(pa + (size_t)(cbase + lane) * 8, &lsA[buf][cbase * 8]);
      GLDS16(pb + (size_t)(cbase + lane) * 8, &lsB[buf][cbase * 8]);
    }
  };

  STAGE(0, 0);
  __syncthreads();

  for (int kt = 0; kt < DIM / 64; ++kt) {
    const int cur = kt & 1;
    if (kt < DIM / 64 - 1) STAGE(cur ^ 1, kt + 1);

    const ushort* bA = &lsA[cur][0];
    const ushort* bB = &lsB[cur][0];
    #pragma unroll
    for (int ks = 0; ks < 2; ++ks) {
      const int gidx = ks * 4 + kgrp;        // logical k-chunk for this frag
      bf16x8 af[4], bfr[4];
      #pragma unroll
      for (int mi = 0; mi < 4; ++mi) {
        int r_ = wm * 64 + mi * 16 + l15;
        af[mi] = *(const bf16x8*)(bA + (r_ * 8 + (gidx ^ (r_ & 7))) * 8);
      }
      #pragma unroll
      for (int ni = 0; ni < 4; ++ni) {
        int c_ = wn * 64 + ni * 16 + l15;
        bfr[ni] = *(const bf16x8*)(bB + (c_ * 8 + (gidx ^ (c_ & 7))) * 8);
      }
      #pragma unroll
      for (int mi = 0; mi < 4; ++mi)
        #pragma unroll
        for (int ni = 0; ni < 4; ++ni)
          acc[mi][ni] = __builtin_amdgcn_mfma_f32_16x16x32_bf16(af[mi], bfr[ni], acc[mi][ni], 0, 0, 0);
    }
    __syncthreads();
  }

  // --- epilogue: per-row top-2 over this block's 128 columns ---
  const int colBase = bn * 128;
  const int rowBase = bm * 128;
  float    c2v[4];
  uint32_t colv[4];
  #pragma unroll
  for (int ni = 0; ni < 4; ++ni) {
    colv[ni] = (uint32_t)(colBase + wn * 64 + ni * 16 + l15);
    c2v[ni]  = c2[colv[ni]];
  }

  #pragma unroll
  for (int mi = 0; mi < 4; ++mi) {
    #pragma unroll
    for (int r = 0; r < 4; ++r) {
      float s0 = c2v[0] - 2.0f * acc[mi][0][r];
      float s1 = c2v[1] - 2.0f * acc[mi][1][r];
      float s2 = c2v[2] - 2.0f * acc[mi][2][r];
      float s3 = c2v[3] - 2.0f * acc[mi][3][r];
      uint64_t a = packKey(s0, colv[0]);
      uint64_t b = packKey(s1, colv[1]);
      uint64_t c = packKey(s2, colv[2]);
      uint64_t d = packKey(s3, colv[3]);
      uint64_t lo1 = umin64(a, b), hi1 = umax64(a, b);
      uint64_t lo2 = umin64(c, d), hi2 = umax64(c, d);
      uint64_t k1 = umin64(lo1, lo2);
      uint64_t k2 = umin64(umax64(lo1, lo2), umin64(hi1, hi2));
      #pragma unroll
      for (int m = 1; m < 16; m <<= 1) {
        uint64_t o1 = __shfl_xor((unsigned long long)k1, m);
        uint64_t o2 = __shfl_xor((unsigned long long)k2, m);
        uint64_t n1 = umin64(k1, o1);
        uint64_t n2 = umin64(umax64(k1, o1), umin64(k2, o2));
        k1 = n1; k2 = n2;
      }
      if (l15 == 0) {
        int rl = wm * 64 + mi * 16 + kgrp * 4 + r;
        redbuf[wn][rl][0] = k1;
        redbuf[wn][rl][1] = k2;
      }
    }
  }
  __syncthreads();

  if (t < 128) {
    uint64_t a1 = redbuf[0][t][0], a2 = redbuf[0][t][1];
    uint64_t b1 = redbuf[1][t][0], b2 = redbuf[1][t][1];
    uint64_t m1 = umin64(a1, b1);
    uint64_t m2 = umin64(umax64(a1, b1), umin64(a2, b2));
    size_t o = (size_t)(rowBase + t) * (2 * NBLK) + (size_t)bn * 2;
    cand[o]     = m1;
    cand[o + 1] = m2;
  }
}

// ---------------- kernel 1 (fallback): on-the-fly conversion version (R1, known-good) ----------------
__global__ __launch_bounds__(256) void snap_gemm_slow(const float* __restrict__ x,
                                                      const float* __restrict__ cb,
                                                      const float* __restrict__ c2,
                                                      uint64_t* __restrict__ cand) {
  __shared__ ushort lsA[2][8192];
  __shared__ ushort lsB[2][8192];
  __shared__ uint64_t redbuf[2][128][2];

  const int t    = threadIdx.x;
  const int lane = t & 63;
  const int wid  = t >> 6;
  const int wm   = wid & 1;
  const int wn   = wid >> 1;
  const int l15  = lane & 15;
  const int kgrp = lane >> 4;

  const int bm = blockIdx.x & 127;
  const int bn = blockIdx.x >> 7;
  const int rowBase = bm * 128;
  const int colBase = bn * 128;

  const float* aptr[4];
  const float* bptr[4];
  int ldsOff[4];
  #pragma unroll
  for (int i = 0; i < 4; ++i) {
    int pc = t + 256 * i;
    int row = pc >> 3;
    int g = (pc & 7) ^ (row & 7);
    aptr[i] = x  + (size_t)(rowBase + row) * DIM + g * 8;
    bptr[i] = cb + (size_t)(colBase + row) * DIM + g * 8;
    ldsOff[i] = pc * 8;
  }

  f32x4 acc[4][4];
  #pragma unroll
  for (int mi = 0; mi < 4; ++mi)
    #pragma unroll
    for (int ni = 0; ni < 4; ++ni)
      acc[mi][ni] = (f32x4){0.f, 0.f, 0.f, 0.f};

  auto STAGE = [&](int buf, int kt) {
    const int kOff = kt * 64;
    #pragma unroll
    for (int i = 0; i < 4; ++i) {
      f32x4 a0 = *(const f32x4*)(aptr[i] + kOff);
      f32x4 a1 = *(const f32x4*)(aptr[i] + kOff + 4);
      f32x4 b0 = *(const f32x4*)(bptr[i] + kOff);
      f32x4 b1 = *(const f32x4*)(bptr[i] + kOff + 4);
      bf16x8 pa, pb;
      #pragma unroll
      for (int j = 0; j < 4; ++j) {
        pa[j]     = (short)f2bf(a0[j]);
        pa[j + 4] = (short)f2bf(a1[j]);
        pb[j]     = (short)f2bf(b0[j]);
        pb[j + 4] = (short)f2bf(b1[j]);
      }
      *(bf16x8*)(&lsA[buf][ldsOff[i]]) = pa;
      *(bf16x8*)(&lsB[buf][ldsOff[i]]) = pb;
    }
  };

  STAGE(0, 0);
  __syncthreads();

  for (int kt = 0; kt < DIM / 64; ++kt) {
    const int cur = kt & 1;
    if (kt < DIM / 64 - 1) STAGE(cur ^ 1, kt + 1);

    const ushort* bA = &lsA[cur][0];
    const ushort* bB = &lsB[cur][0];
    #pragma unroll
    for (int ks = 0; ks < 2; ++ks) {
      const int gidx = ks * 4 + kgrp;
      bf16x8 af[4], bfr[4];
      #pragma unroll
      for (int mi = 0; mi < 4; ++mi) {
        int r_ = wm * 64 + mi * 16 + l15;
        af[mi] = *(const bf16x8*)(bA + (r_ * 8 + (gidx ^ (r_ & 7))) * 8);
      }
      #pragma unroll
      for (int ni = 0; ni < 4; ++ni) {
        int c_ = wn * 64 + ni * 16 + l15;
        bfr[ni] = *(const bf16x8*)(bB + (c_ * 8 + (gidx ^ (c_ & 7))) * 8);
      }
      #pragma unroll
      for (int mi = 0; mi < 4; ++mi)
        #pragma unroll
        for (int ni = 0; ni < 4; ++ni)
          acc[mi][ni] = __builtin_amdgcn_mfma_f32_16x16x32_bf16(af[mi], bfr[ni], acc[mi][ni], 0, 0, 0);
    }
    __syncthreads();
  }

  float    c2v[4];
  uint32_t colv[4];
  #pragma unroll
  for (int ni = 0; ni < 4; ++ni) {
    colv[ni] = (uint32_t)(colBase + wn * 64 + ni * 16 + l15);
    c2v[ni]  = c2[colv[ni]];
  }

  #pragma unroll
  for (int mi = 0; mi < 4; ++mi) {
    #pragma unroll
    for (int r = 0; r < 4; ++r) {
      float s0 = c2v[0] - 2.0f * acc[mi][0][r];
      float s1 = c2v[1] - 2.0f * acc[mi][1][r];
      float s2 = c2v[2] - 2.0f * acc[mi][2][r];
      float s3 = c2v[3] - 2.0f * acc[mi][3][r];
      uint64_t a = packKey(s0, colv[0]);
      uint64_t b = packKey(s1, colv[1]);
      uint64_t c = packKey(s2, colv[2]);
      uint64_t d = packKey(s3, colv[3]);
      uint64_t lo1 = umin64(a, b), hi1 = umax64(a, b);
      uint64_t lo2 = umin64(c, d), hi2 = umax64(c, d);
      uint64_t k1 = umin64(lo1, lo2);
      uint64_t k2 = umin64(umax64(lo1, lo2), umin64(hi1, hi2));
      #pragma unroll
      for (int m = 1; m < 16; m <<= 1) {
        uint64_t o1 = __shfl_xor((unsigned long long)k1, m);
        uint64_t o2 = __shfl_xor((unsigned long long)k2, m);
        uint64_t n1 = umin64(k1, o1);
        uint64_t n2 = umin64(umax64(k1, o1), umin64(k2, o2));
        k1 = n1; k2 = n2;
      }
      if (l15 == 0) {
        int rl = wm * 64 + mi * 16 + kgrp * 4 + r;
        redbuf[wn][rl][0] = k1;
        redbuf[wn][rl][1] = k2;
      }
    }
  }
  __syncthreads();

  if (t < 128) {
    uint64_t a1 = redbuf[0][t][0], a2 = redbuf[0][t][1];
    uint64_t b1 = redbuf[1][t][0], b2 = redbuf[1][t][1];
    uint64_t m1 = umin64(a1, b1);
    uint64_t m2 = umin64(umax64(a1, b1), umin64(a2, b2));
    size_t o = (size_t)(rowBase + t) * (2 * NBLK) + (size_t)bn * 2;
    cand[o]     = m1;
    cand[o + 1] = m2;
  }
}

// ---------------- kernel 2: exact f64 rerank of candidates within MARGIN of pool-min ----------------
__global__ __launch_bounds__(256) void rerank(const float* __restrict__ x,
                                              const float* __restrict__ cb,
                                              const uint64_t* __restrict__ cand,
                                              int* __restrict__ bestidx) {
  const int row = blockIdx.x;
  const int t = threadIdx.x, lane = t & 63, wid = t >> 6;
  __shared__ uint64_t smin[4];
  __shared__ uint64_t gshared;
  __shared__ double   dpart[4];
  __shared__ int      cnt;
  __shared__ int      list[64];

  uint64_t my = cand[(size_t)row * 256 + t];
  uint64_t k = my;
  #pragma unroll
  for (int off = 32; off; off >>= 1) {
    uint64_t o = __shfl_down((unsigned long long)k, off);
    if (o < k) k = o;
  }
  if (lane == 0) smin[wid] = k;
  if (t == 0) cnt = 0;
  __syncthreads();
  if (t == 0) {
    uint64_t g = smin[0];
    for (int i = 1; i < 4; ++i) if (smin[i] < g) g = smin[i];
    gshared = g;
  }
  __syncthreads();

  float gval = unpackVal(gshared);
  if (unpackVal(my) <= gval + MARGIN) {
    int p = atomicAdd(&cnt, 1);
    if (p < 64) list[p] = (int)(uint32_t)(my & 0xFFFFFFFFu);
  }
  __syncthreads();
  int n = cnt; if (n > 64) n = 64;

  uint64_t best = ~0ull;
  const float* xr = x + (size_t)row * DIM;
  for (int i = 0; i < n; ++i) {
    const int cidx = list[i];
    const float* cr = cb + (size_t)cidx * DIM;
    double p = 0.0;
    #pragma unroll
    for (int j = 0; j < 4; ++j) {
      int d = t + 256 * j;
      double diff = (double)xr[d] - (double)cr[d];
      p += diff * diff;
    }
    #pragma unroll
    for (int off = 32; off; off >>= 1) p += __shfl_down(p, off);
    if (lane == 0) dpart[wid] = p;
    __syncthreads();
    if (t == 0) {
      double d2 = dpart[0] + dpart[1] + dpart[2] + dpart[3];
      uint64_t bits = (uint64_t)__double_as_longlong(d2);   // d2 >= 0: bits are order-preserving
      uint64_t key = (bits & ~0x3FFFull) | (uint32_t)cidx;  // low 14 bits: index (tie -> lowest idx)
      if (key < best) best = key;
    }
    __syncthreads();
  }
  if (t == 0) bestidx[row] = (int)(best & 0x3FFFull);
}

// ---------------- kernel 3: gather winning codebook rows ----------------
__global__ __launch_bounds__(256) void gather_rows(const float* __restrict__ cb,
                                                   const int* __restrict__ bestidx,
                                                   float* __restrict__ out) {
  const int row = blockIdx.x;
  const int idx = bestidx[row];
  f32x4 v = *(const f32x4*)(cb + (size_t)idx * DIM + threadIdx.x * 4);
  *(f32x4*)(out + (size_t)row * DIM + threadIdx.x * 4) = v;
}

extern "C" void kernel_launch(void* const* d_in, const int* in_sizes, int n_in,
                              void* d_out, int out_size, void* d_ws, size_t ws_size,
                              hipStream_t stream) {
  const float* x  = (const float*)d_in[0];
  const float* cb = (const float*)d_in[1];
  float* out = (float*)d_out;

  float* c2      = (float*)d_ws;                        // 64 KB
  int*   bestidx = (int*)((char*)d_ws + 64 * 1024);     // 64 KB

  const size_t candBytes = (size_t)NROWS * 256 * 8;     // 32 MB
  const size_t needFast  = 128 * 1024 + candBytes;

  c2_kernel<<<NCODES, 256, 0, stream>>>(cb, c2);

  if (ws_size >= needFast) {
    // Fast path: bf16 copies (pre-swizzled, tile-blocked) fill d_out; cand in d_ws.
    ushort* xs = (ushort*)d_out;                        // 33.5 MB
    ushort* cs = xs + (size_t)NROWS * DIM;              // 33.5 MB
    uint64_t* cand = (uint64_t*)((char*)d_ws + 128 * 1024);

    convert_swz<<<8192, 256, 0, stream>>>(x,  xs);
    convert_swz<<<8192, 256, 0, stream>>>(cb, cs);
    snap_gemm_fast<<<(NROWS / 128) * (NCODES / 128), 256, 0, stream>>>(xs, cs, c2, cand);
    rerank<<<NROWS, 256, 0, stream>>>(x, cb, cand, bestidx);
    gather_rows<<<NROWS, 256, 0, stream>>>(cb, bestidx, out);
  } else {
    // Fallback (R1 known-good): cand pool lives in d_out, overwritten by gather at the end.
    uint64_t* cand = (uint64_t*)d_out;
    snap_gemm_slow<<<(NROWS / 128) * (NCODES / 128), 256, 0, stream>>>(x, cb, c2, cand);
    rerank<<<NROWS, 256, 0, stream>>>(x, cb, cand, bestidx);
    gather_rows<<<NROWS, 256, 0, stream>>>(cb, bestidx, out);
  }
}

// Round 3
// 872.612 us; speedup vs baseline: 1.6155x; 1.0779x over previous
//
#include <hip/hip_runtime.h>
#include <hip/hip_bf16.h>
#include <stdint.h>

// x: (4,4096,1024) f32 -> 16384 x 1024 rows; codebook: (16384,1024) f32
#define NROWS  16384
#define NCODES 16384
#define DIM    1024
#define MARGIN 3.0f
#define NT     16          // DIM / BK,  BK = 64
#define TCH    2048        // 16B chunks per 256x64 tile

typedef float f32x4  __attribute__((ext_vector_type(4)));
typedef short bf16x8 __attribute__((ext_vector_type(8)));

__device__ __forceinline__ ushort f2bf(float f) {
  uint32_t u = __float_as_uint(f);
  uint32_t r = u + 0x7FFFu + ((u >> 16) & 1u);
  return (ushort)(r >> 16);
}
__device__ __forceinline__ uint64_t umin64(uint64_t a, uint64_t b){ return a < b ? a : b; }
__device__ __forceinline__ uint64_t umax64(uint64_t a, uint64_t b){ return a < b ? b : a; }
__device__ __forceinline__ uint64_t packKey(float v, uint32_t idx) {
  uint32_t b = __float_as_uint(v);
  b = (b & 0x80000000u) ? ~b : (b | 0x80000000u);
  return ((uint64_t)b << 32) | idx;
}
__device__ __forceinline__ float unpackVal(uint64_t k) {
  uint32_t b = (uint32_t)(k >> 32);
  b = (b & 0x80000000u) ? (b & 0x7FFFFFFFu) : ~b;
  return __uint_as_float(b);
}

#define GLDS16(gp, lp) \
  __builtin_amdgcn_global_load_lds((const __attribute__((address_space(1))) void*)(gp), \
                                   (__attribute__((address_space(3))) void*)(lp), 16, 0, 0)

// barrier with compiler memory fence + sched fence (raw s_barrier: no vmcnt drain)
__device__ __forceinline__ void sbar() {
  asm volatile("" ::: "memory");
  __builtin_amdgcn_sched_barrier(0);
  __builtin_amdgcn_s_barrier();
  __builtin_amdgcn_sched_barrier(0);
  asm volatile("" ::: "memory");
}

// ---------------- kernel 0: c2[c] = sum(codebook[c]^2) ----------------
__global__ __launch_bounds__(256) void c2_kernel(const float* __restrict__ cb,
                                                 float* __restrict__ c2) {
  const int code = blockIdx.x;
  const int t = threadIdx.x, lane = t & 63, wid = t >> 6;
  f32x4 v = *(const f32x4*)(cb + (size_t)code * DIM + t * 4);
  float s = v[0]*v[0] + v[1]*v[1] + v[2]*v[2] + v[3]*v[3];
  #pragma unroll
  for (int off = 32; off; off >>= 1) s += __shfl_down(s, off);
  __shared__ float part[4];
  if (lane == 0) part[wid] = s;
  __syncthreads();
  if (t == 0) c2[code] = part[0] + part[1] + part[2] + part[3];
}

// ---------------- kernel 0b: f32 -> bf16, pre-swizzled 256x64-tile-blocked layout ----------------
// tile (m,kt): chunks [(m*16+kt)*2048 .. +2048), chunk pc holds row=pc>>3,
// logical k-chunk g = (pc&7) ^ (row&7)  (XOR swizzle baked into global layout).
__global__ __launch_bounds__(256) void convert_swz256(const float* __restrict__ src,
                                                      ushort* __restrict__ dst) {
  const int chunk = blockIdx.x * 256 + threadIdx.x;   // [0, 64*16*2048)
  const int pc  = chunk & 2047;
  const int kt  = (chunk >> 11) & 15;
  const int m   = chunk >> 15;
  const int row = pc >> 3;
  const int g   = (pc & 7) ^ (row & 7);
  const float* s = src + (size_t)(m * 256 + row) * DIM + kt * 64 + g * 8;
  f32x4 a0 = *(const f32x4*)s;
  f32x4 a1 = *(const f32x4*)(s + 4);
  bf16x8 p;
  #pragma unroll
  for (int j = 0; j < 4; ++j) {
    p[j]     = (short)f2bf(a0[j]);
    p[j + 4] = (short)f2bf(a1[j]);
  }
  *(bf16x8*)(dst + (size_t)chunk * 8) = p;
}

// ---------------- kernel 1: 256^2 8-phase bf16 MFMA GEMM + per-(row,256-block) top-2 ----------------
#define STAGE_HALF(LS, BASE, KT, H) do {                                          \
    _Pragma("unroll")                                                             \
    for (int i_ = 0; i_ < 2; ++i_) {                                              \
      const int cb_ = (H) * 1024 + (i_ * 8 + w) * 64;                             \
      GLDS16((BASE) + (size_t)((KT) * TCH + cb_ + lane) * 8, &(LS)[cb_ * 8]);     \
    } } while (0)

#define RD_A4(DST, LS, MIB) do {                                                  \
    _Pragma("unroll")                                                             \
    for (int mi_ = 0; mi_ < 4; ++mi_) {                                           \
      _Pragma("unroll")                                                           \
      for (int ks_ = 0; ks_ < 2; ++ks_) {                                         \
        const int r_ = wm * 128 + ((MIB) + mi_) * 16 + l15;                       \
        const int g_ = ks_ * 4 + kgrp;                                            \
        DST[mi_][ks_] = *(const bf16x8*)&(LS)[(r_ * 8 + (g_ ^ (r_ & 7))) * 8];    \
      } } } while (0)

#define RD_B2(DST, LS, NIB) do {                                                  \
    _Pragma("unroll")                                                             \
    for (int ni_ = 0; ni_ < 2; ++ni_) {                                           \
      _Pragma("unroll")                                                           \
      for (int ks_ = 0; ks_ < 2; ++ks_) {                                         \
        const int c_ = wn * 64 + ((NIB) + ni_) * 16 + l15;                        \
        const int g_ = ks_ * 4 + kgrp;                                            \
        DST[ni_][ks_] = *(const bf16x8*)&(LS)[(c_ * 8 + (g_ ^ (c_ & 7))) * 8];    \
      } } } while (0)

#define MMA_Q(MB, NB, AF, BF) do {                                                \
    __builtin_amdgcn_s_setprio(1);                                                \
    _Pragma("unroll")                                                             \
    for (int mi_ = 0; mi_ < 4; ++mi_) {                                           \
      _Pragma("unroll")                                                           \
      for (int ni_ = 0; ni_ < 2; ++ni_) {                                         \
        _Pragma("unroll")                                                         \
        for (int ks_ = 0; ks_ < 2; ++ks_)                                         \
          acc[(MB) + mi_][(NB) + ni_] = __builtin_amdgcn_mfma_f32_16x16x32_bf16(  \
              AF[mi_][ks_], BF[ni_][ks_], acc[(MB) + mi_][(NB) + ni_], 0, 0, 0);  \
      } }                                                                         \
    __builtin_amdgcn_s_setprio(0);                                                \
  } while (0)

__global__ __launch_bounds__(512, 2) void snap_gemm256(const ushort* __restrict__ xs,
                                                       const ushort* __restrict__ cs,
                                                       const float* __restrict__ c2,
                                                       uint64_t* __restrict__ cand) {
  __shared__ ushort lsA[2][16384];   // 2 x (256 rows x 64 k) bf16, chunk-swizzled
  __shared__ ushort lsB[2][16384];

  const int t    = threadIdx.x;
  const int lane = t & 63;
  const int w    = t >> 6;          // 0..7
  const int wm   = w >> 2;          // 0..1  (rows wm*128..+128)
  const int wn   = w & 3;           // 0..3  (cols wn*64..+64)
  const int l15  = lane & 15;
  const int kgrp = lane >> 4;

  // XCD-aware swizzle: 4096 blocks, 8 XCDs, 512 per XCD (bijective: 4096%8==0)
  const int bid = blockIdx.x;
  const int swz = (bid & 7) * 512 + (bid >> 3);
  const int bm  = swz & 63;
  const int bn  = swz >> 6;

  const ushort* xbase = xs + (size_t)bm * (16 * TCH) * 8;
  const ushort* cbase = cs + (size_t)bn * (16 * TCH) * 8;

  f32x4 acc[8][4];
  #pragma unroll
  for (int mi = 0; mi < 8; ++mi)
    #pragma unroll
    for (int ni = 0; ni < 4; ++ni)
      acc[mi][ni] = (f32x4){0.f, 0.f, 0.f, 0.f};

  bf16x8 aF[4][2], bF0[2][2], bF1[2][2];

  // ---- prologue: tile0 full (8 loads) + tile1 B halves (4 loads) ----
  STAGE_HALF(lsA[0], xbase, 0, 0);
  STAGE_HALF(lsA[0], xbase, 0, 1);
  STAGE_HALF(lsB[0], cbase, 0, 0);
  STAGE_HALF(lsB[0], cbase, 0, 1);
  STAGE_HALF(lsB[1], cbase, 1, 0);
  STAGE_HALF(lsB[1], cbase, 1, 1);
  asm volatile("s_waitcnt vmcnt(4)" ::: "memory");   // tile0 landed; B(1) may fly
  sbar();

  // Steady-state stage cadence at tile t (buf b = t&1):
  //   P0: A-lo(t+1) -> lsA[b^1]   P1: A-hi(t+1) -> lsA[b^1]
  //   P2: B-lo(t+2) -> lsB[b]     P3: B-hi(t+2) -> lsB[b]
  // Guard at P3 end: vmcnt(4) leaves only B(t+2) halves in flight.
  for (int kt = 0; kt < NT; ++kt) {
    const int b = kt & 1;
    const ushort* curA = lsA[b];
    const ushort* curB = lsB[b];
    ushort* nxtA = lsA[b ^ 1];
    ushort* curBst = lsB[b];

    // ---- P0: read A(mi0-3) + B(ni0-1); stage A-lo(t+1) ----
    RD_A4(aF, curA, 0);
    RD_B2(bF0, curB, 0);
    if (kt + 1 < NT) STAGE_HALF(nxtA, xbase, kt + 1, 0);
    sbar();
    MMA_Q(0, 0, aF, bF0);
    sbar();

    // ---- P1: read B(ni2-3); stage A-hi(t+1) ----
    RD_B2(bF1, curB, 2);
    if (kt + 1 < NT) STAGE_HALF(nxtA, xbase, kt + 1, 1);
    sbar();
    MMA_Q(0, 2, aF, bF1);
    sbar();

    // ---- P2: read A(mi4-7); stage B-lo(t+2) ----
    RD_A4(aF, curA, 4);
    if (kt + 2 < NT) STAGE_HALF(curBst, cbase, kt + 2, 0);
    sbar();
    MMA_Q(4, 0, aF, bF0);
    sbar();

    // ---- P3: no reads; stage B-hi(t+2) ----
    if (kt + 2 < NT) STAGE_HALF(curBst, cbase, kt + 2, 1);
    sbar();
    MMA_Q(4, 2, aF, bF1);
    if (kt < NT - 2)       { asm volatile("s_waitcnt vmcnt(4)" ::: "memory"); }
    else if (kt == NT - 2) { asm volatile("s_waitcnt vmcnt(0)" ::: "memory"); }
    sbar();
  }

  __syncthreads();   // full drain before overlaying redbuf on lsA

  // ---- epilogue: per-row top-2 over this block's 256 columns ----
  uint64_t* red = (uint64_t*)&lsA[0][0];   // [wn][256 rows][2] = 16 KB
  float    c2v[4];
  uint32_t colv[4];
  #pragma unroll
  for (int ni = 0; ni < 4; ++ni) {
    colv[ni] = (uint32_t)(bn * 256 + wn * 64 + ni * 16 + l15);
    c2v[ni]  = c2[colv[ni]];
  }

  #pragma unroll
  for (int mi = 0; mi < 8; ++mi) {
    #pragma unroll
    for (int r = 0; r < 4; ++r) {
      float s0 = c2v[0] - 2.0f * acc[mi][0][r];
      float s1 = c2v[1] - 2.0f * acc[mi][1][r];
      float s2 = c2v[2] - 2.0f * acc[mi][2][r];
      float s3 = c2v[3] - 2.0f * acc[mi][3][r];
      uint64_t a = packKey(s0, colv[0]);
      uint64_t b_ = packKey(s1, colv[1]);
      uint64_t c = packKey(s2, colv[2]);
      uint64_t d = packKey(s3, colv[3]);
      uint64_t lo1 = umin64(a, b_), hi1 = umax64(a, b_);
      uint64_t lo2 = umin64(c, d),  hi2 = umax64(c, d);
      uint64_t k1 = umin64(lo1, lo2);
      uint64_t k2 = umin64(umax64(lo1, lo2), umin64(hi1, hi2));
      #pragma unroll
      for (int m = 1; m < 16; m <<= 1) {
        uint64_t o1 = __shfl_xor((unsigned long long)k1, m);
        uint64_t o2 = __shfl_xor((unsigned long long)k2, m);
        uint64_t n1 = umin64(k1, o1);
        uint64_t n2 = umin64(umax64(k1, o1), umin64(k2, o2));
        k1 = n1; k2 = n2;
      }
      if (l15 == 0) {
        int rl = wm * 128 + mi * 16 + kgrp * 4 + r;
        red[(wn * 256 + rl) * 2 + 0] = k1;
        red[(wn * 256 + rl) * 2 + 1] = k2;
      }
    }
  }
  __syncthreads();

  if (t < 256) {
    uint64_t k1 = red[(0 * 256 + t) * 2 + 0];
    uint64_t k2 = red[(0 * 256 + t) * 2 + 1];
    #pragma unroll
    for (int q = 1; q < 4; ++q) {
      uint64_t p1 = red[(q * 256 + t) * 2 + 0];
      uint64_t p2 = red[(q * 256 + t) * 2 + 1];
      uint64_t n1 = umin64(k1, p1);
      uint64_t n2 = umin64(umax64(k1, p1), umin64(k2, p2));
      k1 = n1; k2 = n2;
    }
    size_t o = (size_t)(bm * 256 + t) * 128 + (size_t)bn * 2;
    cand[o]     = k1;
    cand[o + 1] = k2;
  }
}

// ---------------- kernel 1 (fallback, R1 known-good): on-the-fly conversion 128^2 ----------------
__global__ __launch_bounds__(256) void snap_gemm_slow(const float* __restrict__ x,
                                                      const float* __restrict__ cb,
                                                      const float* __restrict__ c2,
                                                      uint64_t* __restrict__ cand) {
  __shared__ ushort lsA[2][8192];
  __shared__ ushort lsB[2][8192];
  __shared__ uint64_t redbuf[2][128][2];

  const int t    = threadIdx.x;
  const int lane = t & 63;
  const int wid  = t >> 6;
  const int wm   = wid & 1;
  const int wn   = wid >> 1;
  const int l15  = lane & 15;
  const int kgrp = lane >> 4;

  const int bm = blockIdx.x & 127;
  const int bn = blockIdx.x >> 7;
  const int rowBase = bm * 128;
  const int colBase = bn * 128;

  const float* aptr[4];
  const float* bptr[4];
  int ldsOff[4];
  #pragma unroll
  for (int i = 0; i < 4; ++i) {
    int pc = t + 256 * i;
    int row = pc >> 3;
    int g = (pc & 7) ^ (row & 7);
    aptr[i] = x  + (size_t)(rowBase + row) * DIM + g * 8;
    bptr[i] = cb + (size_t)(colBase + row) * DIM + g * 8;
    ldsOff[i] = pc * 8;
  }

  f32x4 acc[4][4];
  #pragma unroll
  for (int mi = 0; mi < 4; ++mi)
    #pragma unroll
    for (int ni = 0; ni < 4; ++ni)
      acc[mi][ni] = (f32x4){0.f, 0.f, 0.f, 0.f};

  auto STAGE = [&](int buf, int kt) {
    const int kOff = kt * 64;
    #pragma unroll
    for (int i = 0; i < 4; ++i) {
      f32x4 a0 = *(const f32x4*)(aptr[i] + kOff);
      f32x4 a1 = *(const f32x4*)(aptr[i] + kOff + 4);
      f32x4 b0 = *(const f32x4*)(bptr[i] + kOff);
      f32x4 b1 = *(const f32x4*)(bptr[i] + kOff + 4);
      bf16x8 pa, pb;
      #pragma unroll
      for (int j = 0; j < 4; ++j) {
        pa[j]     = (short)f2bf(a0[j]);
        pa[j + 4] = (short)f2bf(a1[j]);
        pb[j]     = (short)f2bf(b0[j]);
        pb[j + 4] = (short)f2bf(b1[j]);
      }
      *(bf16x8*)(&lsA[buf][ldsOff[i]]) = pa;
      *(bf16x8*)(&lsB[buf][ldsOff[i]]) = pb;
    }
  };

  STAGE(0, 0);
  __syncthreads();

  for (int kt = 0; kt < DIM / 64; ++kt) {
    const int cur = kt & 1;
    if (kt < DIM / 64 - 1) STAGE(cur ^ 1, kt + 1);

    const ushort* bA = &lsA[cur][0];
    const ushort* bB = &lsB[cur][0];
    #pragma unroll
    for (int ks = 0; ks < 2; ++ks) {
      const int gidx = ks * 4 + kgrp;
      bf16x8 af[4], bfr[4];
      #pragma unroll
      for (int mi = 0; mi < 4; ++mi) {
        int r_ = wm * 64 + mi * 16 + l15;
        af[mi] = *(const bf16x8*)(bA + (r_ * 8 + (gidx ^ (r_ & 7))) * 8);
      }
      #pragma unroll
      for (int ni = 0; ni < 4; ++ni) {
        int c_ = wn * 64 + ni * 16 + l15;
        bfr[ni] = *(const bf16x8*)(bB + (c_ * 8 + (gidx ^ (c_ & 7))) * 8);
      }
      #pragma unroll
      for (int mi = 0; mi < 4; ++mi)
        #pragma unroll
        for (int ni = 0; ni < 4; ++ni)
          acc[mi][ni] = __builtin_amdgcn_mfma_f32_16x16x32_bf16(af[mi], bfr[ni], acc[mi][ni], 0, 0, 0);
    }
    __syncthreads();
  }

  float    c2v[4];
  uint32_t colv[4];
  #pragma unroll
  for (int ni = 0; ni < 4; ++ni) {
    colv[ni] = (uint32_t)(colBase + wn * 64 + ni * 16 + l15);
    c2v[ni]  = c2[colv[ni]];
  }

  #pragma unroll
  for (int mi = 0; mi < 4; ++mi) {
    #pragma unroll
    for (int r = 0; r < 4; ++r) {
      float s0 = c2v[0] - 2.0f * acc[mi][0][r];
      float s1 = c2v[1] - 2.0f * acc[mi][1][r];
      float s2 = c2v[2] - 2.0f * acc[mi][2][r];
      float s3 = c2v[3] - 2.0f * acc[mi][3][r];
      uint64_t a = packKey(s0, colv[0]);
      uint64_t b = packKey(s1, colv[1]);
      uint64_t c = packKey(s2, colv[2]);
      uint64_t d = packKey(s3, colv[3]);
      uint64_t lo1 = umin64(a, b), hi1 = umax64(a, b);
      uint64_t lo2 = umin64(c, d), hi2 = umax64(c, d);
      uint64_t k1 = umin64(lo1, lo2);
      uint64_t k2 = umin64(umax64(lo1, lo2), umin64(hi1, hi2));
      #pragma unroll
      for (int m = 1; m < 16; m <<= 1) {
        uint64_t o1 = __shfl_xor((unsigned long long)k1, m);
        uint64_t o2 = __shfl_xor((unsigned long long)k2, m);
        uint64_t n1 = umin64(k1, o1);
        uint64_t n2 = umin64(umax64(k1, o1), umin64(k2, o2));
        k1 = n1; k2 = n2;
      }
      if (l15 == 0) {
        int rl = wm * 64 + mi * 16 + kgrp * 4 + r;
        redbuf[wn][rl][0] = k1;
        redbuf[wn][rl][1] = k2;
      }
    }
  }
  __syncthreads();

  if (t < 128) {
    uint64_t a1 = redbuf[0][t][0], a2 = redbuf[0][t][1];
    uint64_t b1 = redbuf[1][t][0], b2 = redbuf[1][t][1];
    uint64_t m1 = umin64(a1, b1);
    uint64_t m2 = umin64(umax64(a1, b1), umin64(a2, b2));
    size_t o = (size_t)(rowBase + t) * 256 + (size_t)bn * 2;
    cand[o]     = m1;
    cand[o + 1] = m2;
  }
}

// ---------------- kernel 2: exact f64 rerank of candidates within MARGIN of pool-min ----------------
__global__ __launch_bounds__(256) void rerank(const float* __restrict__ x,
                                              const float* __restrict__ cb,
                                              const uint64_t* __restrict__ cand,
                                              int* __restrict__ bestidx,
                                              int poolN) {
  const int row = blockIdx.x;
  const int t = threadIdx.x, lane = t & 63, wid = t >> 6;
  __shared__ uint64_t smin[4];
  __shared__ uint64_t gshared;
  __shared__ double   dpart[4];
  __shared__ int      cnt;
  __shared__ int      list[64];

  uint64_t my = (t < poolN) ? cand[(size_t)row * poolN + t] : ~0ull;
  uint64_t k = my;
  #pragma unroll
  for (int off = 32; off; off >>= 1) {
    uint64_t o = __shfl_down((unsigned long long)k, off);
    if (o < k) k = o;
  }
  if (lane == 0) smin[wid] = k;
  if (t == 0) cnt = 0;
  __syncthreads();
  if (t == 0) {
    uint64_t g = smin[0];
    for (int i = 1; i < 4; ++i) if (smin[i] < g) g = smin[i];
    gshared = g;
  }
  __syncthreads();

  float gval = unpackVal(gshared);
  if (unpackVal(my) <= gval + MARGIN) {
    int p = atomicAdd(&cnt, 1);
    if (p < 64) list[p] = (int)(uint32_t)(my & 0xFFFFFFFFu);
  }
  __syncthreads();
  int n = cnt; if (n > 64) n = 64;

  uint64_t best = ~0ull;
  const float* xr = x + (size_t)row * DIM;
  for (int i = 0; i < n; ++i) {
    const int cidx = list[i];
    const float* cr = cb + (size_t)cidx * DIM;
    double p = 0.0;
    #pragma unroll
    for (int j = 0; j < 4; ++j) {
      int d = t + 256 * j;
      double diff = (double)xr[d] - (double)cr[d];
      p += diff * diff;
    }
    #pragma unroll
    for (int off = 32; off; off >>= 1) p += __shfl_down(p, off);
    if (lane == 0) dpart[wid] = p;
    __syncthreads();
    if (t == 0) {
      double d2 = dpart[0] + dpart[1] + dpart[2] + dpart[3];
      uint64_t bits = (uint64_t)__double_as_longlong(d2);
      uint64_t key = (bits & ~0x3FFFull) | (uint32_t)cidx;
      if (key < best) best = key;
    }
    __syncthreads();
  }
  if (t == 0) bestidx[row] = (int)(best & 0x3FFFull);
}

// ---------------- kernel 3: gather winning codebook rows ----------------
__global__ __launch_bounds__(256) void gather_rows(const float* __restrict__ cb,
                                                   const int* __restrict__ bestidx,
                                                   float* __restrict__ out) {
  const int row = blockIdx.x;
  const int idx = bestidx[row];
  f32x4 v = *(const f32x4*)(cb + (size_t)idx * DIM + threadIdx.x * 4);
  *(f32x4*)(out + (size_t)row * DIM + threadIdx.x * 4) = v;
}

extern "C" void kernel_launch(void* const* d_in, const int* in_sizes, int n_in,
                              void* d_out, int out_size, void* d_ws, size_t ws_size,
                              hipStream_t stream) {
  const float* x  = (const float*)d_in[0];
  const float* cb = (const float*)d_in[1];
  float* out = (float*)d_out;

  float* c2      = (float*)d_ws;                        // 64 KB
  int*   bestidx = (int*)((char*)d_ws + 64 * 1024);     // 64 KB

  const size_t candBytes = (size_t)NROWS * 128 * 8;     // 16 MB
  const size_t needFast  = 128 * 1024 + candBytes;

  c2_kernel<<<NCODES, 256, 0, stream>>>(cb, c2);

  if (ws_size >= needFast) {
    ushort* xs = (ushort*)d_out;                        // 33.5 MB (bf16, tile-blocked+swizzled)
    ushort* cs = xs + (size_t)NROWS * DIM;              // 33.5 MB
    uint64_t* cand = (uint64_t*)((char*)d_ws + 128 * 1024);

    convert_swz256<<<8192, 256, 0, stream>>>(x,  xs);
    convert_swz256<<<8192, 256, 0, stream>>>(cb, cs);
    snap_gemm256<<<4096, 512, 0, stream>>>(xs, cs, c2, cand);
    rerank<<<NROWS, 256, 0, stream>>>(x, cb, cand, bestidx, 128);
    gather_rows<<<NROWS, 256, 0, stream>>>(cb, bestidx, out);
  } else {
    uint64_t* cand = (uint64_t*)d_out;
    snap_gemm_slow<<<(NROWS / 128) * (NCODES / 128), 256, 0, stream>>>(x, cb, c2, cand);
    rerank<<<NROWS, 256, 0, stream>>>(x, cb, cand, bestidx, 256);
    gather_rows<<<NROWS, 256, 0, stream>>>(cb, bestidx, out);
  }
}

// Round 4
// 785.425 us; speedup vs baseline: 1.7948x; 1.1110x over previous
//
#include <hip/hip_runtime.h>
#include <hip/hip_bf16.h>
#include <stdint.h>

// x: (4,4096,1024) f32 -> 16384 x 1024 rows; codebook: (16384,1024) f32
#define NROWS  16384
#define NCODES 16384
#define DIM    1024
#define MARGIN 3.0f
#define NT     16          // DIM / BK,  BK = 64
#define TCH    2048        // 16B chunks per 256x64 tile

typedef float f32x4  __attribute__((ext_vector_type(4)));
typedef short bf16x8 __attribute__((ext_vector_type(8)));

__device__ __forceinline__ ushort f2bf(float f) {
  uint32_t u = __float_as_uint(f);
  uint32_t r = u + 0x7FFFu + ((u >> 16) & 1u);
  return (ushort)(r >> 16);
}
__device__ __forceinline__ uint64_t umin64(uint64_t a, uint64_t b){ return a < b ? a : b; }
__device__ __forceinline__ uint64_t umax64(uint64_t a, uint64_t b){ return a < b ? b : a; }
__device__ __forceinline__ uint64_t packKey(float v, uint32_t idx) {
  uint32_t b = __float_as_uint(v);
  b = (b & 0x80000000u) ? ~b : (b | 0x80000000u);
  return ((uint64_t)b << 32) | idx;
}
__device__ __forceinline__ float unpackVal(uint64_t k) {
  uint32_t b = (uint32_t)(k >> 32);
  b = (b & 0x80000000u) ? (b & 0x7FFFFFFFu) : ~b;
  return __uint_as_float(b);
}

#define GLDS16(gp, lp) \
  __builtin_amdgcn_global_load_lds((const __attribute__((address_space(1))) void*)(gp), \
                                   (__attribute__((address_space(3))) void*)(lp), 16, 0, 0)

// barrier with compiler memory fence only — NO sched_barrier(0) (m141 lesson)
__device__ __forceinline__ void sbar() {
  asm volatile("" ::: "memory");
  __builtin_amdgcn_s_barrier();
  asm volatile("" ::: "memory");
}

// ---------------- kernel 0: c2[c] = sum(codebook[c]^2) ----------------
__global__ __launch_bounds__(256) void c2_kernel(const float* __restrict__ cb,
                                                 float* __restrict__ c2) {
  const int code = blockIdx.x;
  const int t = threadIdx.x, lane = t & 63, wid = t >> 6;
  f32x4 v = *(const f32x4*)(cb + (size_t)code * DIM + t * 4);
  float s = v[0]*v[0] + v[1]*v[1] + v[2]*v[2] + v[3]*v[3];
  #pragma unroll
  for (int off = 32; off; off >>= 1) s += __shfl_down(s, off);
  __shared__ float part[4];
  if (lane == 0) part[wid] = s;
  __syncthreads();
  if (t == 0) c2[code] = part[0] + part[1] + part[2] + part[3];
}

// ---------------- kernel 0b: f32 -> bf16, pre-swizzled 256x64-tile-blocked layout ----------------
// tile (m,kt): chunks [(m*16+kt)*2048 .. +2048), chunk pc holds row=pc>>3,
// logical k-chunk g = (pc&7) ^ (row&7)  (XOR swizzle baked into global layout).
__global__ __launch_bounds__(256) void convert_swz256(const float* __restrict__ src,
                                                      ushort* __restrict__ dst) {
  const int chunk = blockIdx.x * 256 + threadIdx.x;   // [0, 64*16*2048)
  const int pc  = chunk & 2047;
  const int kt  = (chunk >> 11) & 15;
  const int m   = chunk >> 15;
  const int row = pc >> 3;
  const int g   = (pc & 7) ^ (row & 7);
  const float* s = src + (size_t)(m * 256 + row) * DIM + kt * 64 + g * 8;
  f32x4 a0 = *(const f32x4*)s;
  f32x4 a1 = *(const f32x4*)(s + 4);
  bf16x8 p;
  #pragma unroll
  for (int j = 0; j < 4; ++j) {
    p[j]     = (short)f2bf(a0[j]);
    p[j + 4] = (short)f2bf(a1[j]);
  }
  *(bf16x8*)(dst + (size_t)chunk * 8) = p;
}

// ---------------- kernel 1: 256^2 8-phase bf16 MFMA GEMM + per-(row,256-block) top-2 ----------------
#define STAGE_HALF(LS, BASE, KT, H) do {                                          \
    _Pragma("unroll")                                                             \
    for (int i_ = 0; i_ < 2; ++i_) {                                              \
      const int cb_ = (H) * 1024 + (i_ * 8 + w) * 64;                             \
      GLDS16((BASE) + (size_t)((KT) * TCH + cb_ + lane) * 8, &(LS)[cb_ * 8]);     \
    } } while (0)

#define RD_A4(DST, LS, MIB) do {                                                  \
    _Pragma("unroll")                                                             \
    for (int mi_ = 0; mi_ < 4; ++mi_) {                                           \
      _Pragma("unroll")                                                           \
      for (int ks_ = 0; ks_ < 2; ++ks_) {                                         \
        const int r_ = wm * 128 + ((MIB) + mi_) * 16 + l15;                       \
        const int g_ = ks_ * 4 + kgrp;                                            \
        DST[mi_][ks_] = *(const bf16x8*)&(LS)[(r_ * 8 + (g_ ^ (r_ & 7))) * 8];    \
      } } } while (0)

#define RD_B2(DST, LS, NIB) do {                                                  \
    _Pragma("unroll")                                                             \
    for (int ni_ = 0; ni_ < 2; ++ni_) {                                           \
      _Pragma("unroll")                                                           \
      for (int ks_ = 0; ks_ < 2; ++ks_) {                                         \
        const int c_ = wn * 64 + ((NIB) + ni_) * 16 + l15;                        \
        const int g_ = ks_ * 4 + kgrp;                                            \
        DST[ni_][ks_] = *(const bf16x8*)&(LS)[(c_ * 8 + (g_ ^ (c_ & 7))) * 8];    \
      } } } while (0)

#define MMA_Q(MB, NB, AF, BF) do {                                                \
    __builtin_amdgcn_s_setprio(1);                                                \
    _Pragma("unroll")                                                             \
    for (int mi_ = 0; mi_ < 4; ++mi_) {                                           \
      _Pragma("unroll")                                                           \
      for (int ni_ = 0; ni_ < 2; ++ni_) {                                         \
        _Pragma("unroll")                                                         \
        for (int ks_ = 0; ks_ < 2; ++ks_)                                         \
          acc[(MB) + mi_][(NB) + ni_] = __builtin_amdgcn_mfma_f32_16x16x32_bf16(  \
              AF[mi_][ks_], BF[ni_][ks_], acc[(MB) + mi_][(NB) + ni_], 0, 0, 0);  \
      } }                                                                         \
    __builtin_amdgcn_s_setprio(0);                                                \
  } while (0)

__global__ __launch_bounds__(512, 2) void snap_gemm256(const ushort* __restrict__ xs,
                                                       const ushort* __restrict__ cs,
                                                       const float* __restrict__ c2,
                                                       uint64_t* __restrict__ cand) {
  __shared__ ushort lsA[3][16384];   // 3-deep A ring (96 KB): A staged 2 tiles ahead
  __shared__ ushort lsB[2][16384];   // 2-deep B (64 KB):      B staged 2 tiles ahead

  const int t    = threadIdx.x;
  const int lane = t & 63;
  const int w    = t >> 6;          // 0..7
  const int wm   = w >> 2;          // 0..1  (rows wm*128..+128)
  const int wn   = w & 3;           // 0..3  (cols wn*64..+64)
  const int l15  = lane & 15;
  const int kgrp = lane >> 4;

  // XCD-aware swizzle: 4096 blocks, 8 XCDs, 512 per XCD (bijective: 4096%8==0)
  const int bid = blockIdx.x;
  const int swz = (bid & 7) * 512 + (bid >> 3);
  const int bm  = swz & 63;
  const int bn  = swz >> 6;

  const ushort* xbase = xs + (size_t)bm * (16 * TCH) * 8;
  const ushort* cbase = cs + (size_t)bn * (16 * TCH) * 8;

  f32x4 acc[8][4];
  #pragma unroll
  for (int mi = 0; mi < 8; ++mi)
    #pragma unroll
    for (int ni = 0; ni < 4; ++ni)
      acc[mi][ni] = (f32x4){0.f, 0.f, 0.f, 0.f};

  bf16x8 aF[4][2], bF0[2][2], bF1[2][2];

  // ---- prologue: {A(0),B(0)} then {A(1),B(1)}; wait for the first 8 ops ----
  STAGE_HALF(lsA[0], xbase, 0, 0);
  STAGE_HALF(lsA[0], xbase, 0, 1);
  STAGE_HALF(lsB[0], cbase, 0, 0);
  STAGE_HALF(lsB[0], cbase, 0, 1);
  STAGE_HALF(lsA[1], xbase, 1, 0);
  STAGE_HALF(lsA[1], xbase, 1, 1);
  STAGE_HALF(lsB[1], cbase, 1, 0);
  STAGE_HALF(lsB[1], cbase, 1, 1);
  asm volatile("s_waitcnt vmcnt(8)" ::: "memory");   // tile0 landed; tile1 may fly
  sbar();

  // Steady state, tile t: read lsA[t%3], lsB[t%2]; stage A(t+2)->lsA[(t+2)%3],
  // B(t+2)->lsB[t%2] (B buf free after P1's reads). Guard vmcnt(8) at P3 keeps
  // this tile's 8 staging ops in flight, forces everything older (= tile t+1's
  // operands) to have landed. Flight time: A ~7 phases, B ~5 phases.
  for (int kt = 0; kt < NT; ++kt) {
    const ushort* curA = lsA[kt % 3];
    const ushort* curB = lsB[kt & 1];
    ushort* nxtA = lsA[(kt + 2) % 3];
    ushort* nxtB = lsB[kt & 1];
    const bool st = (kt + 2 < NT);

    // ---- P0: read A(mi0-3) + B(ni0-1); stage A(t+2)-lo ----
    RD_A4(aF, curA, 0);
    RD_B2(bF0, curB, 0);
    if (st) STAGE_HALF(nxtA, xbase, kt + 2, 0);
    sbar();
    MMA_Q(0, 0, aF, bF0);
    sbar();

    // ---- P1: read B(ni2-3); stage A(t+2)-hi ----
    RD_B2(bF1, curB, 2);
    if (st) STAGE_HALF(nxtA, xbase, kt + 2, 1);
    sbar();
    MMA_Q(0, 2, aF, bF1);
    sbar();

    // ---- P2: read A(mi4-7); stage B(t+2)-lo ----
    RD_A4(aF, curA, 4);
    if (st) STAGE_HALF(nxtB, cbase, kt + 2, 0);
    sbar();
    MMA_Q(4, 0, aF, bF0);
    sbar();

    // ---- P3: stage B(t+2)-hi; MFMA; guard ----
    if (st) STAGE_HALF(nxtB, cbase, kt + 2, 1);
    sbar();
    MMA_Q(4, 2, aF, bF1);
    if (st)                { asm volatile("s_waitcnt vmcnt(8)" ::: "memory"); }
    else if (kt == NT - 2) { asm volatile("s_waitcnt vmcnt(0)" ::: "memory"); }
    sbar();
  }

  __syncthreads();   // full drain before overlaying redbuf on lsA

  // ---- epilogue: per-row top-2 over this block's 256 columns ----
  uint64_t* red = (uint64_t*)&lsA[0][0];   // [wn][256 rows][2] = 16 KB
  float    c2v[4];
  uint32_t colv[4];
  #pragma unroll
  for (int ni = 0; ni < 4; ++ni) {
    colv[ni] = (uint32_t)(bn * 256 + wn * 64 + ni * 16 + l15);
    c2v[ni]  = c2[colv[ni]];
  }

  #pragma unroll
  for (int mi = 0; mi < 8; ++mi) {
    #pragma unroll
    for (int r = 0; r < 4; ++r) {
      float s0 = c2v[0] - 2.0f * acc[mi][0][r];
      float s1 = c2v[1] - 2.0f * acc[mi][1][r];
      float s2 = c2v[2] - 2.0f * acc[mi][2][r];
      float s3 = c2v[3] - 2.0f * acc[mi][3][r];
      uint64_t a = packKey(s0, colv[0]);
      uint64_t b_ = packKey(s1, colv[1]);
      uint64_t c = packKey(s2, colv[2]);
      uint64_t d = packKey(s3, colv[3]);
      uint64_t lo1 = umin64(a, b_), hi1 = umax64(a, b_);
      uint64_t lo2 = umin64(c, d),  hi2 = umax64(c, d);
      uint64_t k1 = umin64(lo1, lo2);
      uint64_t k2 = umin64(umax64(lo1, lo2), umin64(hi1, hi2));
      #pragma unroll
      for (int m = 1; m < 16; m <<= 1) {
        uint64_t o1 = __shfl_xor((unsigned long long)k1, m);
        uint64_t o2 = __shfl_xor((unsigned long long)k2, m);
        uint64_t n1 = umin64(k1, o1);
        uint64_t n2 = umin64(umax64(k1, o1), umin64(k2, o2));
        k1 = n1; k2 = n2;
      }
      if (l15 == 0) {
        int rl = wm * 128 + mi * 16 + kgrp * 4 + r;
        red[(wn * 256 + rl) * 2 + 0] = k1;
        red[(wn * 256 + rl) * 2 + 1] = k2;
      }
    }
  }
  __syncthreads();

  if (t < 256) {
    uint64_t k1 = red[(0 * 256 + t) * 2 + 0];
    uint64_t k2 = red[(0 * 256 + t) * 2 + 1];
    #pragma unroll
    for (int q = 1; q < 4; ++q) {
      uint64_t p1 = red[(q * 256 + t) * 2 + 0];
      uint64_t p2 = red[(q * 256 + t) * 2 + 1];
      uint64_t n1 = umin64(k1, p1);
      uint64_t n2 = umin64(umax64(k1, p1), umin64(k2, p2));
      k1 = n1; k2 = n2;
    }
    size_t o = (size_t)(bm * 256 + t) * 128 + (size_t)bn * 2;
    cand[o]     = k1;
    cand[o + 1] = k2;
  }
}

// ---------------- kernel 1 (fallback, R1 known-good): on-the-fly conversion 128^2 ----------------
__global__ __launch_bounds__(256) void snap_gemm_slow(const float* __restrict__ x,
                                                      const float* __restrict__ cb,
                                                      const float* __restrict__ c2,
                                                      uint64_t* __restrict__ cand) {
  __shared__ ushort lsA[2][8192];
  __shared__ ushort lsB[2][8192];
  __shared__ uint64_t redbuf[2][128][2];

  const int t    = threadIdx.x;
  const int lane = t & 63;
  const int wid  = t >> 6;
  const int wm   = wid & 1;
  const int wn   = wid >> 1;
  const int l15  = lane & 15;
  const int kgrp = lane >> 4;

  const int bm = blockIdx.x & 127;
  const int bn = blockIdx.x >> 7;
  const int rowBase = bm * 128;
  const int colBase = bn * 128;

  const float* aptr[4];
  const float* bptr[4];
  int ldsOff[4];
  #pragma unroll
  for (int i = 0; i < 4; ++i) {
    int pc = t + 256 * i;
    int row = pc >> 3;
    int g = (pc & 7) ^ (row & 7);
    aptr[i] = x  + (size_t)(rowBase + row) * DIM + g * 8;
    bptr[i] = cb + (size_t)(colBase + row) * DIM + g * 8;
    ldsOff[i] = pc * 8;
  }

  f32x4 acc[4][4];
  #pragma unroll
  for (int mi = 0; mi < 4; ++mi)
    #pragma unroll
    for (int ni = 0; ni < 4; ++ni)
      acc[mi][ni] = (f32x4){0.f, 0.f, 0.f, 0.f};

  auto STAGE = [&](int buf, int kt) {
    const int kOff = kt * 64;
    #pragma unroll
    for (int i = 0; i < 4; ++i) {
      f32x4 a0 = *(const f32x4*)(aptr[i] + kOff);
      f32x4 a1 = *(const f32x4*)(aptr[i] + kOff + 4);
      f32x4 b0 = *(const f32x4*)(bptr[i] + kOff);
      f32x4 b1 = *(const f32x4*)(bptr[i] + kOff + 4);
      bf16x8 pa, pb;
      #pragma unroll
      for (int j = 0; j < 4; ++j) {
        pa[j]     = (short)f2bf(a0[j]);
        pa[j + 4] = (short)f2bf(a1[j]);
        pb[j]     = (short)f2bf(b0[j]);
        pb[j + 4] = (short)f2bf(b1[j]);
      }
      *(bf16x8*)(&lsA[buf][ldsOff[i]]) = pa;
      *(bf16x8*)(&lsB[buf][ldsOff[i]]) = pb;
    }
  };

  STAGE(0, 0);
  __syncthreads();

  for (int kt = 0; kt < DIM / 64; ++kt) {
    const int cur = kt & 1;
    if (kt < DIM / 64 - 1) STAGE(cur ^ 1, kt + 1);

    const ushort* bA = &lsA[cur][0];
    const ushort* bB = &lsB[cur][0];
    #pragma unroll
    for (int ks = 0; ks < 2; ++ks) {
      const int gidx = ks * 4 + kgrp;
      bf16x8 af[4], bfr[4];
      #pragma unroll
      for (int mi = 0; mi < 4; ++mi) {
        int r_ = wm * 64 + mi * 16 + l15;
        af[mi] = *(const bf16x8*)(bA + (r_ * 8 + (gidx ^ (r_ & 7))) * 8);
      }
      #pragma unroll
      for (int ni = 0; ni < 4; ++ni) {
        int c_ = wn * 64 + ni * 16 + l15;
        bfr[ni] = *(const bf16x8*)(bB + (c_ * 8 + (gidx ^ (c_ & 7))) * 8);
      }
      #pragma unroll
      for (int mi = 0; mi < 4; ++mi)
        #pragma unroll
        for (int ni = 0; ni < 4; ++ni)
          acc[mi][ni] = __builtin_amdgcn_mfma_f32_16x16x32_bf16(af[mi], bfr[ni], acc[mi][ni], 0, 0, 0);
    }
    __syncthreads();
  }

  float    c2v[4];
  uint32_t colv[4];
  #pragma unroll
  for (int ni = 0; ni < 4; ++ni) {
    colv[ni] = (uint32_t)(colBase + wn * 64 + ni * 16 + l15);
    c2v[ni]  = c2[colv[ni]];
  }

  #pragma unroll
  for (int mi = 0; mi < 4; ++mi) {
    #pragma unroll
    for (int r = 0; r < 4; ++r) {
      float s0 = c2v[0] - 2.0f * acc[mi][0][r];
      float s1 = c2v[1] - 2.0f * acc[mi][1][r];
      float s2 = c2v[2] - 2.0f * acc[mi][2][r];
      float s3 = c2v[3] - 2.0f * acc[mi][3][r];
      uint64_t a = packKey(s0, colv[0]);
      uint64_t b = packKey(s1, colv[1]);
      uint64_t c = packKey(s2, colv[2]);
      uint64_t d = packKey(s3, colv[3]);
      uint64_t lo1 = umin64(a, b), hi1 = umax64(a, b);
      uint64_t lo2 = umin64(c, d), hi2 = umax64(c, d);
      uint64_t k1 = umin64(lo1, lo2);
      uint64_t k2 = umin64(umax64(lo1, lo2), umin64(hi1, hi2));
      #pragma unroll
      for (int m = 1; m < 16; m <<= 1) {
        uint64_t o1 = __shfl_xor((unsigned long long)k1, m);
        uint64_t o2 = __shfl_xor((unsigned long long)k2, m);
        uint64_t n1 = umin64(k1, o1);
        uint64_t n2 = umin64(umax64(k1, o1), umin64(k2, o2));
        k1 = n1; k2 = n2;
      }
      if (l15 == 0) {
        int rl = wm * 64 + mi * 16 + kgrp * 4 + r;
        redbuf[wn][rl][0] = k1;
        redbuf[wn][rl][1] = k2;
      }
    }
  }
  __syncthreads();

  if (t < 128) {
    uint64_t a1 = redbuf[0][t][0], a2 = redbuf[0][t][1];
    uint64_t b1 = redbuf[1][t][0], b2 = redbuf[1][t][1];
    uint64_t m1 = umin64(a1, b1);
    uint64_t m2 = umin64(umax64(a1, b1), umin64(a2, b2));
    size_t o = (size_t)(rowBase + t) * 256 + (size_t)bn * 2;
    cand[o]     = m1;
    cand[o + 1] = m2;
  }
}

// ---------------- kernel 2: exact f64 rerank of candidates within MARGIN of pool-min ----------------
__global__ __launch_bounds__(256) void rerank(const float* __restrict__ x,
                                              const float* __restrict__ cb,
                                              const uint64_t* __restrict__ cand,
                                              int* __restrict__ bestidx,
                                              int poolN) {
  const int row = blockIdx.x;
  const int t = threadIdx.x, lane = t & 63, wid = t >> 6;
  __shared__ uint64_t smin[4];
  __shared__ uint64_t gshared;
  __shared__ double   dpart[4];
  __shared__ int      cnt;
  __shared__ int      list[64];

  uint64_t my = (t < poolN) ? cand[(size_t)row * poolN + t] : ~0ull;
  uint64_t k = my;
  #pragma unroll
  for (int off = 32; off; off >>= 1) {
    uint64_t o = __shfl_down((unsigned long long)k, off);
    if (o < k) k = o;
  }
  if (lane == 0) smin[wid] = k;
  if (t == 0) cnt = 0;
  __syncthreads();
  if (t == 0) {
    uint64_t g = smin[0];
    for (int i = 1; i < 4; ++i) if (smin[i] < g) g = smin[i];
    gshared = g;
  }
  __syncthreads();

  float gval = unpackVal(gshared);
  if (unpackVal(my) <= gval + MARGIN) {
    int p = atomicAdd(&cnt, 1);
    if (p < 64) list[p] = (int)(uint32_t)(my & 0xFFFFFFFFu);
  }
  __syncthreads();
  int n = cnt; if (n > 64) n = 64;

  uint64_t best = ~0ull;
  const float* xr = x + (size_t)row * DIM;
  for (int i = 0; i < n; ++i) {
    const int cidx = list[i];
    const float* cr = cb + (size_t)cidx * DIM;
    double p = 0.0;
    #pragma unroll
    for (int j = 0; j < 4; ++j) {
      int d = t + 256 * j;
      double diff = (double)xr[d] - (double)cr[d];
      p += diff * diff;
    }
    #pragma unroll
    for (int off = 32; off; off >>= 1) p += __shfl_down(p, off);
    if (lane == 0) dpart[wid] = p;
    __syncthreads();
    if (t == 0) {
      double d2 = dpart[0] + dpart[1] + dpart[2] + dpart[3];
      uint64_t bits = (uint64_t)__double_as_longlong(d2);
      uint64_t key = (bits & ~0x3FFFull) | (uint32_t)cidx;
      if (key < best) best = key;
    }
    __syncthreads();
  }
  if (t == 0) bestidx[row] = (int)(best & 0x3FFFull);
}

// ---------------- kernel 3: gather winning codebook rows ----------------
__global__ __launch_bounds__(256) void gather_rows(const float* __restrict__ cb,
                                                   const int* __restrict__ bestidx,
                                                   float* __restrict__ out) {
  const int row = blockIdx.x;
  const int idx = bestidx[row];
  f32x4 v = *(const f32x4*)(cb + (size_t)idx * DIM + threadIdx.x * 4);
  *(f32x4*)(out + (size_t)row * DIM + threadIdx.x * 4) = v;
}

extern "C" void kernel_launch(void* const* d_in, const int* in_sizes, int n_in,
                              void* d_out, int out_size, void* d_ws, size_t ws_size,
                              hipStream_t stream) {
  const float* x  = (const float*)d_in[0];
  const float* cb = (const float*)d_in[1];
  float* out = (float*)d_out;

  float* c2      = (float*)d_ws;                        // 64 KB
  int*   bestidx = (int*)((char*)d_ws + 64 * 1024);     // 64 KB

  const size_t candBytes = (size_t)NROWS * 128 * 8;     // 16 MB
  const size_t needFast  = 128 * 1024 + candBytes;

  c2_kernel<<<NCODES, 256, 0, stream>>>(cb, c2);

  if (ws_size >= needFast) {
    ushort* xs = (ushort*)d_out;                        // 33.5 MB (bf16, tile-blocked+swizzled)
    ushort* cs = xs + (size_t)NROWS * DIM;              // 33.5 MB
    uint64_t* cand = (uint64_t*)((char*)d_ws + 128 * 1024);

    convert_swz256<<<8192, 256, 0, stream>>>(x,  xs);
    convert_swz256<<<8192, 256, 0, stream>>>(cb, cs);
    snap_gemm256<<<4096, 512, 0, stream>>>(xs, cs, c2, cand);
    rerank<<<NROWS, 256, 0, stream>>>(x, cb, cand, bestidx, 128);
    gather_rows<<<NROWS, 256, 0, stream>>>(cb, bestidx, out);
  } else {
    uint64_t* cand = (uint64_t*)d_out;
    snap_gemm_slow<<<(NROWS / 128) * (NCODES / 128), 256, 0, stream>>>(x, cb, c2, cand);
    rerank<<<NROWS, 256, 0, stream>>>(x, cb, cand, bestidx, 256);
    gather_rows<<<NROWS, 256, 0, stream>>>(cb, bestidx, out);
  }
}